// Round 5
// baseline (2930.151 us; speedup 1.0000x reference)
//
#include <hip/hip_runtime.h>
#include <cstdint>
#include <cstddef>
#include <cstdio>

using u32 = unsigned int;
using u16 = unsigned short;
typedef __attribute__((ext_vector_type(8))) short short8;   // 8 x bf16 (4 VGPRs)
typedef __attribute__((ext_vector_type(4))) float f32x4;

// ---------- constants ----------
#define TT    4096
#define CC    512
#define DPROJ 2208
#define NPAD  2304        // 18 * 128
#define BT    32768       // B*T

// ---------- bf16 helpers ----------
__device__ __forceinline__ u16 f2b(float f) {
  u32 u = __float_as_uint(f);
  u32 r = (u + 0x7FFFu + ((u >> 16) & 1u)) >> 16;
  return (u16)r;
}
__device__ __forceinline__ float b2f(u16 s) { return __uint_as_float(((u32)s) << 16); }
__device__ __forceinline__ u32 pack2(float lo, float hi) {
  return (u32)f2b(lo) | ((u32)f2b(hi) << 16);
}
__device__ __forceinline__ float getf4(const float4& v, int i) {
  return i == 0 ? v.x : i == 1 ? v.y : i == 2 ? v.z : v.w;
}

// ---------- K0: weight convert fp32 -> bf16 (W1 padded to 2304 rows) ----------
__global__ __launch_bounds__(256) void k_wconv(
    const float* __restrict__ W1in, const float* __restrict__ W2in,
    u16* __restrict__ w1, u16* __restrict__ w2)
{
  int i = blockIdx.x * 256 + threadIdx.x;           // exact grid: 2304*512 + 512*1024
  if (i < NPAD * CC) {
    int n = i >> 9;                                  // row (k = i & 511)
    int src = (i < DPROJ * CC) ? i : 0;              // CLAMPED: no speculative OOB read
    float v = W1in[src];
    w1[i] = (n < DPROJ) ? f2b(v) : (u16)0;
  } else {
    int j = i - NPAD * CC;                           // < 512*1024
    w2[j] = f2b(W2in[j]);
  }
}

// ---------- K1: RMSNorm over C=512, write bf16 ----------
__global__ __launch_bounds__(64) void k_rms(
    const float* __restrict__ in, const float* __restrict__ w, u16* __restrict__ o)
{
  const int row = blockIdx.x, lane = threadIdx.x;
  const float* ip = in + (size_t)row * CC + lane * 8;
  float4 v0 = *(const float4*)ip;
  float4 v1 = *(const float4*)(ip + 4);
  float ss = v0.x*v0.x + v0.y*v0.y + v0.z*v0.z + v0.w*v0.w
           + v1.x*v1.x + v1.y*v1.y + v1.z*v1.z + v1.w*v1.w;
#pragma unroll
  for (int m = 1; m < 64; m <<= 1) ss += __shfl_xor(ss, m);
  float sc = rsqrtf(ss * (1.f / 512.f) + 1e-5f);
  const float* wp = w + lane * 8;
  float4 w0 = *(const float4*)wp;
  float4 w1 = *(const float4*)(wp + 4);
  uint4 ov;
  ov.x = pack2(v0.x*sc*w0.x, v0.y*sc*w0.y);
  ov.y = pack2(v0.z*sc*w0.z, v0.w*sc*w0.w);
  ov.z = pack2(v1.x*sc*w1.x, v1.y*sc*w1.y);
  ov.w = pack2(v1.z*sc*w1.z, v1.w*sc*w1.w);
  *(uint4*)(o + (size_t)row * CC + lane * 8) = ov;
}

// ---------- K2/K5: bf16 MFMA GEMM, C = A @ B^T (B stored [N][K]) ----------
__global__ __launch_bounds__(256) void k_gemm(
    const u16* __restrict__ A, const u16* __restrict__ Bm,
    int lda, int ldb, int nk, int ntiles,
    u16* __restrict__ Cb, int ldc,
    float* __restrict__ Cf, const float* __restrict__ resid)
{
  __shared__ u16 As[128 * 32];
  __shared__ u16 Bs[128 * 32];
  const int tid = threadIdx.x;
  const int bx = blockIdx.x % ntiles;
  const int by = blockIdx.x / ntiles;
  const int brow = by * 128, bcol = bx * 128;
  const int lane = tid & 63, w = tid >> 6;
  const int wr = w >> 1, wc = w & 1;
  const int l15 = lane & 15, l4 = lane >> 4;

  f32x4 acc[4][4];
  const f32x4 zero = {0.f, 0.f, 0.f, 0.f};
#pragma unroll
  for (int i = 0; i < 4; ++i)
#pragma unroll
    for (int j = 0; j < 4; ++j) acc[i][j] = zero;

  for (int ks = 0; ks < nk; ++ks) {
    const int k0 = ks * 32;
#pragma unroll
    for (int it = 0; it < 2; ++it) {
      int i = tid + it * 256;          // 512 chunks of 16B per 8KB tile
      int r = i >> 2, cb = i & 3;
      ((uint4*)As)[i] = *(const uint4*)(A + (size_t)(brow + r) * lda + k0 + cb * 8);
      ((uint4*)Bs)[i] = *(const uint4*)(Bm + (size_t)(bcol + r) * ldb + k0 + cb * 8);
    }
    __syncthreads();
    short8 af[4], bfv[4];
#pragma unroll
    for (int mi = 0; mi < 4; ++mi)
      af[mi] = ((const short8*)As)[(wr * 64 + mi * 16 + l15) * 4 + l4];
#pragma unroll
    for (int ni = 0; ni < 4; ++ni)
      bfv[ni] = ((const short8*)Bs)[(wc * 64 + ni * 16 + l15) * 4 + l4];
#pragma unroll
    for (int mi = 0; mi < 4; ++mi)
#pragma unroll
      for (int ni = 0; ni < 4; ++ni)
        acc[mi][ni] = __builtin_amdgcn_mfma_f32_16x16x32_bf16(af[mi], bfv[ni], acc[mi][ni], 0, 0, 0);
    __syncthreads();
  }

  // C/D layout [m89]: col = lane&15, row = (lane>>4)*4 + j
  const int r0 = brow + wr * 64 + l4 * 4;
  const int c0 = bcol + wc * 64 + l15;
#pragma unroll
  for (int mi = 0; mi < 4; ++mi) {
#pragma unroll
    for (int ni = 0; ni < 4; ++ni) {
      int r = r0 + mi * 16;
      int c = c0 + ni * 16;
      if (Cb) {
#pragma unroll
        for (int j = 0; j < 4; ++j)
          Cb[(size_t)(r + j) * ldc + c] = f2b(acc[mi][ni][j]);
      } else {
#pragma unroll
        for (int j = 0; j < 4; ++j) {
          size_t off = (size_t)(r + j) * ldc + c;
          Cf[off] = resid[off] + acc[mi][ni][j];
        }
      }
    }
  }
}

// ---------- K3: per-(b,t): dt=softplus(dt_raw+bias); B/C rmsnorm ----------
__global__ __launch_bounds__(64) void k_derive(
    const u16* __restrict__ zxb, const float* __restrict__ dt_bias,
    const float* __restrict__ Bnw, const float* __restrict__ Cnw,
    float* __restrict__ dtb, float* __restrict__ Bh, float* __restrict__ Ch)
{
  const int row = blockIdx.x, lane = threadIdx.x;
  const u16* zr = zxb + (size_t)row * NPAD;
  float bv = b2f(zr[2048 + lane]);
  float cv = b2f(zr[2112 + lane]);
  float sb = bv * bv, sc2 = cv * cv;
#pragma unroll
  for (int m = 1; m < 64; m <<= 1) { sb += __shfl_xor(sb, m); sc2 += __shfl_xor(sc2, m); }
  Bh[(size_t)row * 64 + lane] = bv * rsqrtf(sb * (1.f / 64.f) + 1e-5f) * Bnw[lane];
  Ch[(size_t)row * 64 + lane] = cv * rsqrtf(sc2 * (1.f / 64.f) + 1e-5f) * Cnw[lane];
  if (lane < 32) {
    float raw = b2f(zr[2176 + lane]) + dt_bias[lane];
    float dtv = (raw > 20.f) ? raw : log1pf(expf(raw));
    dtb[(size_t)row * 32 + lane] = dtv;
  }
}

// ---------- K4: sequential scan, 1 wave per (b,h); chunked LDS rot tables;
//              fused gate epilogue v = (y + D*x)*z ----------
struct Step {
  float4 ac[4];    // 16 a*cos for this lane's j-range (from LDS)
  float4 as4[4];   // 16 a*sin
  float4 Bv[8];    // 32 fp32 B values for this lane's n-range
  float4 Cv[8];    // 32 fp32 C values
  float  xv, zv, dtv;
};

__global__ __launch_bounds__(64, 1) void k_scan(
    const float* __restrict__ dtb, const float* __restrict__ Bh,
    const float* __restrict__ Ch, const u16* __restrict__ zxb,
    const float* __restrict__ omega, const float* __restrict__ A_log,
    const float* __restrict__ Dp, u16* __restrict__ vout)
{
  __shared__ float ac_s[64][32];
  __shared__ float as_s[64][32];
  const int lane = threadIdx.x;
  const int p = lane & 31;
  const int half = lane >> 5;
  const int b = blockIdx.x >> 5;
  const int h = blockIdx.x & 31;
  const size_t row0 = (size_t)b * TT;
  const float eA = expf(A_log[h]);
  const float om = omega[h * 32 + p];    // fill role: this lane's j = p
  const float Dv = Dp[h];

  float st[32];
#pragma unroll
  for (int i = 0; i < 32; ++i) st[i] = 0.f;

  Step s0, s1;

  auto fill = [&](int t0) {
#pragma unroll
    for (int tl = 0; tl < 32; ++tl) {
      int ts = half * 32 + tl;
      float dtv = dtb[(row0 + t0 + ts) * 32 + h];
      float av = expf(-eA * dtv);
      float sn, cn;
      __sincosf(dtv * om, &sn, &cn);
      ac_s[ts][p] = av * cn;             // bank = p: 2 lanes/bank (free)
      as_s[ts][p] = av * sn;
    }
  };

  auto load_step = [&](Step& s, int t) {
    size_t row = row0 + t;
    const float4* bp = (const float4*)(Bh + row * 64 + half * 32);
    const float4* cp = (const float4*)(Ch + row * 64 + half * 32);
#pragma unroll
    for (int i = 0; i < 8; ++i) s.Bv[i] = bp[i];
#pragma unroll
    for (int i = 0; i < 8; ++i) s.Cv[i] = cp[i];
    s.dtv = dtb[row * 32 + h];
    s.xv = b2f(zxb[row * NPAD + 1024 + h * 32 + p]);
    s.zv = b2f(zxb[row * NPAD + h * 32 + p]);
    int ts = t & 63;
    const float4* ap = (const float4*)&ac_s[ts][half * 16];
    const float4* sp = (const float4*)&as_s[ts][half * 16];
#pragma unroll
    for (int i = 0; i < 4; ++i) { s.ac[i] = ap[i]; s.as4[i] = sp[i]; }
  };

  auto compute = [&](const Step& s, int t) {
    float dtx = s.dtv * s.xv;
    float ya = 0.f, yb = 0.f;
#pragma unroll
    for (int ii = 0; ii < 16; ++ii) {
      float acv = getf4(s.ac[ii >> 2], ii & 3);
      float asv = getf4(s.as4[ii >> 2], ii & 3);
      float b0 = getf4(s.Bv[ii >> 1], (ii & 1) * 2);
      float b1 = getf4(s.Bv[ii >> 1], (ii & 1) * 2 + 1);
      float c0 = getf4(s.Cv[ii >> 1], (ii & 1) * 2);
      float c1 = getf4(s.Cv[ii >> 1], (ii & 1) * 2 + 1);
      float h0 = st[2 * ii], h1 = st[2 * ii + 1];
      float t0 = fmaf(acv, h0, fmaf(-asv, h1, dtx * b0));
      float t1 = fmaf(asv, h0, fmaf(acv, h1, dtx * b1));
      st[2 * ii] = t0; st[2 * ii + 1] = t1;
      ya = fmaf(t0, c0, ya);
      yb = fmaf(t1, c1, yb);
    }
    float yp = ya + yb;
    yp += __shfl_xor(yp, 32);
    if (half == 0) {
      float v = (yp + Dv * s.xv) * s.zv;
      vout[(row0 + t) * 1024 + h * 32 + p] = f2b(v);
    }
  };

  for (int c = 0; c < 64; ++c) {
    const int t0 = c * 64;
    __syncthreads();                 // previous chunk's LDS reads retired
    fill(t0);
    __syncthreads();
    load_step(s0, t0);
    for (int ts = 0; ts < 64; ts += 2) {
      load_step(s1, t0 + ts + 1);
      compute(s0, t0 + ts);
      if (ts + 2 < 64) load_step(s0, t0 + ts + 2);
      compute(s1, t0 + ts + 1);
    }
  }
}

// ---------- launch ----------
extern "C" void kernel_launch(void* const* d_in, const int* in_sizes, int n_in,
                              void* d_out, int out_size, void* d_ws, size_t ws_size,
                              hipStream_t stream) {
  const float* input     = (const float*)d_in[0];
  const float* rms_w     = (const float*)d_in[1];
  const float* in_proj_W = (const float*)d_in[2];
  const float* dt_bias   = (const float*)d_in[3];
  const float* A_log     = (const float*)d_in[4];
  const float* omega     = (const float*)d_in[5];
  const float* Dp        = (const float*)d_in[6];
  const float* Bnw       = (const float*)d_in[7];
  const float* Cnw       = (const float*)d_in[8];
  const float* out_proj_W= (const float*)d_in[9];
  float* out = (float*)d_out;

  // ---- workspace layout (bytes), total 242,483,200 (~231.3 MB) ----
  const size_t NEED = 242483200;
  fprintf(stderr, "[kernel] ws_size=%zu need=%zu n_in=%d out_size=%d\n",
          ws_size, NEED, n_in, out_size);
  if (ws_size < NEED) return;   // clean fail with diagnostic instead of fault

  char* ws = (char*)d_ws;
  u16*   zxb  = (u16*)(ws + 0);              // 150,994,944  bf16[BT][2304]
  u16*   nv   = (u16*)(ws + 150994944);      //  67,108,864  normed[BT][512] -> vbuf[BT][1024]
  u16*   w1   = (u16*)(ws + 218103808);      //   2,359,296  bf16[2304][512]
  u16*   w2   = (u16*)(ws + 220463104);      //   1,048,576  bf16[512][1024]
  float* dtb  = (float*)(ws + 221511680);    //   4,194,304  f32[BT][32]
  float* Bh   = (float*)(ws + 225705984);    //   8,388,608  f32[BT][64]
  float* Ch   = (float*)(ws + 234094592);    //   8,388,608  f32[BT][64]
  u16* normed = nv;
  u16* vbuf   = nv;

  k_wconv<<<6656, 256, 0, stream>>>(in_proj_W, out_proj_W, w1, w2);
  k_rms<<<BT, 64, 0, stream>>>(input, rms_w, normed);
  // GEMM1: [BT,512] @ [2304,512]^T -> zxb bf16 [BT,2304]
  k_gemm<<<(BT / 128) * 18, 256, 0, stream>>>(normed, w1, 512, 512, 16, 18,
                                              zxb, NPAD, nullptr, nullptr);
  k_derive<<<BT, 64, 0, stream>>>(zxb, dt_bias, Bnw, Cnw, dtb, Bh, Ch);
  k_scan<<<256, 64, 0, stream>>>(dtb, Bh, Ch, zxb, omega, A_log, Dp, vbuf);
  // GEMM2: [BT,1024] @ [512,1024]^T + input -> out f32 [BT,512]
  k_gemm<<<(BT / 128) * 4, 256, 0, stream>>>(vbuf, w2, 1024, 1024, 32, 4,
                                             nullptr, 512, out, input);
}

// Round 7
// 615.487 us; speedup vs baseline: 4.7607x; 4.7607x over previous
//
#include <hip/hip_runtime.h>
#include <cstdint>
#include <cstddef>
#include <cstdio>

using u32 = unsigned int;
using u16 = unsigned short;
typedef __attribute__((ext_vector_type(8))) short short8;   // 8 x bf16 (4 VGPRs)
typedef __attribute__((ext_vector_type(4))) float f32x4;

// ---------- constants ----------
#define TT    4096
#define CC    512
#define DPROJ 2208
#define NPAD  2304        // 18 * 128
#define BT    32768       // B*T

// ---------- bf16 helpers ----------
__device__ __forceinline__ u16 f2b(float f) {
  u32 u = __float_as_uint(f);
  u32 r = (u + 0x7FFFu + ((u >> 16) & 1u)) >> 16;
  return (u16)r;
}
__device__ __forceinline__ float b2f(u16 s) { return __uint_as_float(((u32)s) << 16); }
__device__ __forceinline__ u32 pack2(float lo, float hi) {
  return (u32)f2b(lo) | ((u32)f2b(hi) << 16);
}
__device__ __forceinline__ float lo2f(u32 u) { return __uint_as_float(u << 16); }
__device__ __forceinline__ float hi2f(u32 u) { return __uint_as_float(u & 0xFFFF0000u); }

__device__ __forceinline__ short8 mk8(const short r[8]) {
  short8 v; v[0]=r[0]; v[1]=r[1]; v[2]=r[2]; v[3]=r[3];
  v[4]=r[4]; v[5]=r[5]; v[6]=r[6]; v[7]=r[7];
  return v;
}
__device__ __forceinline__ short8 neg8(short8 v) {   // negate 8 bf16 (flip sign bits)
  union { short8 s; u32 w[4]; } u; u.s = v;
#pragma unroll
  for (int i = 0; i < 4; ++i) u.w[i] ^= 0x80008000u;
  return u.s;
}

// ---------- K0: weight convert fp32 -> bf16 (W1 padded to 2304 rows) ----------
__global__ __launch_bounds__(256) void k_wconv(
    const float* __restrict__ W1in, const float* __restrict__ W2in,
    u16* __restrict__ w1, u16* __restrict__ w2)
{
  int i = blockIdx.x * 256 + threadIdx.x;
  if (i < NPAD * CC) {
    int n = i >> 9;
    int src = (i < DPROJ * CC) ? i : 0;              // clamped: no speculative OOB
    float v = W1in[src];
    w1[i] = (n < DPROJ) ? f2b(v) : (u16)0;
  } else {
    int j = i - NPAD * CC;
    w2[j] = f2b(W2in[j]);
  }
}

// ---------- K1: RMSNorm over C=512, write bf16 ----------
__global__ __launch_bounds__(64) void k_rms(
    const float* __restrict__ in, const float* __restrict__ w, u16* __restrict__ o)
{
  const int row = blockIdx.x, lane = threadIdx.x;
  const float* ip = in + (size_t)row * CC + lane * 8;
  float4 v0 = *(const float4*)ip;
  float4 v1 = *(const float4*)(ip + 4);
  float ss = v0.x*v0.x + v0.y*v0.y + v0.z*v0.z + v0.w*v0.w
           + v1.x*v1.x + v1.y*v1.y + v1.z*v1.z + v1.w*v1.w;
#pragma unroll
  for (int m = 1; m < 64; m <<= 1) ss += __shfl_xor(ss, m);
  float sc = rsqrtf(ss * (1.f / 512.f) + 1e-5f);
  const float* wp = w + lane * 8;
  float4 w0 = *(const float4*)wp;
  float4 w1 = *(const float4*)(wp + 4);
  uint4 ov;
  ov.x = pack2(v0.x*sc*w0.x, v0.y*sc*w0.y);
  ov.y = pack2(v0.z*sc*w0.z, v0.w*sc*w0.w);
  ov.z = pack2(v1.x*sc*w1.x, v1.y*sc*w1.y);
  ov.w = pack2(v1.z*sc*w1.z, v1.w*sc*w1.w);
  *(uint4*)(o + (size_t)row * CC + lane * 8) = ov;
}

// ---------- bf16 MFMA GEMM, C = A @ B^T (B stored [N][K]) ----------
__global__ __launch_bounds__(256) void k_gemm(
    const u16* __restrict__ A, const u16* __restrict__ Bm,
    int lda, int ldb, int nk, int ntiles,
    u16* __restrict__ Cb, int ldc,
    float* __restrict__ Cf, const float* __restrict__ resid)
{
  __shared__ u16 As[128 * 32];
  __shared__ u16 Bs[128 * 32];
  const int tid = threadIdx.x;
  const int bx = blockIdx.x % ntiles;
  const int by = blockIdx.x / ntiles;
  const int brow = by * 128, bcol = bx * 128;
  const int lane = tid & 63, w = tid >> 6;
  const int wr = w >> 1, wc = w & 1;
  const int l15 = lane & 15, l4 = lane >> 4;

  f32x4 acc[4][4];
  const f32x4 zero = {0.f, 0.f, 0.f, 0.f};
#pragma unroll
  for (int i = 0; i < 4; ++i)
#pragma unroll
    for (int j = 0; j < 4; ++j) acc[i][j] = zero;

  for (int ks = 0; ks < nk; ++ks) {
    const int k0 = ks * 32;
#pragma unroll
    for (int it = 0; it < 2; ++it) {
      int i = tid + it * 256;
      int r = i >> 2, cb = i & 3;
      ((uint4*)As)[i] = *(const uint4*)(A + (size_t)(brow + r) * lda + k0 + cb * 8);
      ((uint4*)Bs)[i] = *(const uint4*)(Bm + (size_t)(bcol + r) * ldb + k0 + cb * 8);
    }
    __syncthreads();
    short8 af[4], bfv[4];
#pragma unroll
    for (int mi = 0; mi < 4; ++mi)
      af[mi] = ((const short8*)As)[(wr * 64 + mi * 16 + l15) * 4 + l4];
#pragma unroll
    for (int ni = 0; ni < 4; ++ni)
      bfv[ni] = ((const short8*)Bs)[(wc * 64 + ni * 16 + l15) * 4 + l4];
#pragma unroll
    for (int mi = 0; mi < 4; ++mi)
#pragma unroll
      for (int ni = 0; ni < 4; ++ni)
        acc[mi][ni] = __builtin_amdgcn_mfma_f32_16x16x32_bf16(af[mi], bfv[ni], acc[mi][ni], 0, 0, 0);
    __syncthreads();
  }

  const int r0 = brow + wr * 64 + l4 * 4;
  const int c0 = bcol + wc * 64 + l15;
#pragma unroll
  for (int mi = 0; mi < 4; ++mi) {
#pragma unroll
    for (int ni = 0; ni < 4; ++ni) {
      int r = r0 + mi * 16;
      int c = c0 + ni * 16;
      if (Cb) {
#pragma unroll
        for (int j = 0; j < 4; ++j)
          Cb[(size_t)(r + j) * ldc + c] = f2b(acc[mi][ni][j]);
      } else {
#pragma unroll
        for (int j = 0; j < 4; ++j) {
          size_t off = (size_t)(r + j) * ldc + c;
          Cf[off] = resid[off] + acc[mi][ni][j];
        }
      }
    }
  }
}

// ---------- K3: per-(b,t): dt=softplus(dt_raw+bias); B/C rmsnorm ----------
__global__ __launch_bounds__(64) void k_derive(
    const u16* __restrict__ zxb, const float* __restrict__ dt_bias,
    const float* __restrict__ Bnw, const float* __restrict__ Cnw,
    float* __restrict__ dtb, float* __restrict__ Bh, float* __restrict__ Ch)
{
  const int row = blockIdx.x, lane = threadIdx.x;
  const u16* zr = zxb + (size_t)row * NPAD;
  float bv = b2f(zr[2048 + lane]);
  float cv = b2f(zr[2112 + lane]);
  float sb = bv * bv, sc2 = cv * cv;
#pragma unroll
  for (int m = 1; m < 64; m <<= 1) { sb += __shfl_xor(sb, m); sc2 += __shfl_xor(sc2, m); }
  Bh[(size_t)row * 64 + lane] = bv * rsqrtf(sb * (1.f / 64.f) + 1e-5f) * Bnw[lane];
  Ch[(size_t)row * 64 + lane] = cv * rsqrtf(sc2 * (1.f / 64.f) + 1e-5f) * Cnw[lane];
  if (lane < 32) {
    float raw = b2f(zr[2176 + lane]) + dt_bias[lane];
    float dtv = (raw > 20.f) ? raw : log1pf(expf(raw));
    dtb[(size_t)row * 32 + lane] = dtv;
  }
}

// =========================================================================
// Chunked rotary-SSD scan. Chunk L=64. Per (b,h): 64 chunks.
// Complex state H[p,j] (j = n-pair), alpha_t = exp(-eA*dt)*e^{i*om_j*dt}.
// In-chunk inclusive cumsum sigma_t of dt:
//   M[t,s] = exp(-eA(sig_t-sig_s)) * (phiC_t . phiB_s)   (s<=t)
//   phiC = [C0*c+C1*s | C0*s-C1*c],  phiB = [B0*c+B1*s | B0*s-B1*c]  (64 dims)
//   y_t = M @ dtx  +  exp(-eA sig_t) * (phiC_t . phiH[p])
//   G[p,j] = e^{i om_j sig63} * sum_s exp(-eA(sig63-sig_s)) e^{-i om sig_s} B_s dtx_s[p]
//   H carried across chunks in K_b:  H <- P63*H + G,  P63 = exp(-eA cds) e^{i om cds}
// GH buffer: per (chain,g) 4KB slot. K_a writes G [64f][32p] bf16 (f=Gr|Gi);
// K_b overwrites with H_pre [32p][64f] bf16 (f=hr|hi); K_c reads as B-frags.
// =========================================================================

// LDS swizzle for 128B-stride rows (G4): byte ^= (row&7)<<4
#define SWZ(row, byte) ((row)*128 + ((byte) ^ (((row)&7)<<4)))

// ---------- K_a: per-chunk G ----------
__global__ __launch_bounds__(64) void k_chunkA(
    const float* __restrict__ dtb, const float* __restrict__ Bh,
    const u16* __restrict__ zxb, const float* __restrict__ omega,
    const float* __restrict__ A_log, u16* __restrict__ GH,
    float* __restrict__ cds)
{
  __shared__ __attribute__((aligned(16))) u16 dtxT[2048];   // [32p][64t] swizzled
  __shared__ float sig_s[64];
  const int lane = threadIdx.x;
  const int gidx = blockIdx.x;              // chain*64 + g
  const int chain = gidx >> 6, g = gidx & 63;
  const int b = chain >> 5, h = chain & 31;
  const size_t row0 = (size_t)b * TT + (size_t)g * 64;
  const int l15 = lane & 15, l4 = lane >> 4;
  const float eA = expf(A_log[h]);

  // per-lane t = lane: dt + inclusive prefix
  const size_t rowt = row0 + lane;
  const float dt = dtb[rowt * 32 + h];
  float sig = dt;
#pragma unroll
  for (int off = 1; off < 64; off <<= 1) {
    float o = __shfl_up(sig, off);
    if (lane >= off) sig += o;
  }
  sig_s[lane] = sig;
  const float cdsv = __shfl(sig, 63);

  // dtxT build (transpose dt*x into LDS)
  const u16* xrow = zxb + rowt * NPAD + 1024 + h * 32;
  uint4 xa = *(const uint4*)xrow, xb = *(const uint4*)(xrow + 8),
        xc = *(const uint4*)(xrow + 16), xd = *(const uint4*)(xrow + 24);
  u32 xw[16] = {xa.x,xa.y,xa.z,xa.w, xb.x,xb.y,xb.z,xb.w,
                xc.x,xc.y,xc.z,xc.w, xd.x,xd.y,xd.z,xd.w};
#pragma unroll
  for (int p = 0; p < 32; ++p) {
    float xv = (p & 1) ? hi2f(xw[p >> 1]) : lo2f(xw[p >> 1]);
    *(u16*)((char*)dtxT + SWZ(p, 2 * lane)) = f2b(dt * xv);
  }
  __syncthreads();

  // decay table for this lane's s-set
  float d8[2][8];
#pragma unroll
  for (int kk = 0; kk < 2; ++kk)
#pragma unroll
    for (int e = 0; e < 8; ++e)
      d8[kk][e] = expf(-eA * (cdsv - sig_s[l4 * 8 + e + kk * 32]));

  // W A-frags: rows f: [0..31]=Br*, [32..63]=Bi* (both * decay)
  short8 wR[2][2], wI[2][2];
#pragma unroll
  for (int miF = 0; miF < 2; ++miF) {
    const int j = miF * 16 + l15;
    const float om = omega[h * 32 + j];
#pragma unroll
    for (int kk = 0; kk < 2; ++kk) {
      short r8[8], i8[8];
#pragma unroll
      for (int e = 0; e < 8; ++e) {
        const int s = l4 * 8 + e + kk * 32;
        const float sgs = sig_s[s];
        float sn, c; __sincosf(om * sgs, &sn, &c);
        const float* bp = Bh + (row0 + s) * 64 + 2 * j;
        const float B0 = bp[0], B1 = bp[1];
        const float d = d8[kk][e];
        r8[e] = (short)f2b((B0 * c + B1 * sn) * d);
        i8[e] = (short)f2b((B1 * c - B0 * sn) * d);
      }
      wR[miF][kk] = mk8(r8); wI[miF][kk] = mk8(i8);
    }
  }

  // G = W @ dtxT^T : out[64f x 32p]
  f32x4 ga[4][2];
  const f32x4 zero = {0.f,0.f,0.f,0.f};
#pragma unroll
  for (int mi = 0; mi < 4; ++mi) { ga[mi][0] = zero; ga[mi][1] = zero; }
#pragma unroll
  for (int kk = 0; kk < 2; ++kk) {
    short8 db[2];
#pragma unroll
    for (int ni = 0; ni < 2; ++ni) {
      const int prow = ni * 16 + l15;
      db[ni] = *(const short8*)((const char*)dtxT + SWZ(prow, l4 * 16 + kk * 64));
    }
#pragma unroll
    for (int mi = 0; mi < 4; ++mi) {
      short8 af = (mi < 2) ? wR[mi][kk] : wI[mi - 2][kk];
#pragma unroll
      for (int ni = 0; ni < 2; ++ni)
        ga[mi][ni] = __builtin_amdgcn_mfma_f32_16x16x32_bf16(af, db[ni], ga[mi][ni], 0, 0, 0);
    }
  }

  // post-rotate by e^{i om sig63}, store G [64f][32p] bf16
  u16* gout = GH + (size_t)gidx * 2048;
#pragma unroll
  for (int miF = 0; miF < 2; ++miF)
#pragma unroll
    for (int reg = 0; reg < 4; ++reg) {
      const int j = miF * 16 + l4 * 4 + reg;
      const float om = omega[h * 32 + j];
      float sn, c; __sincosf(om * cdsv, &sn, &c);
#pragma unroll
      for (int ni = 0; ni < 2; ++ni) {
        const int p = ni * 16 + l15;
        const float Gr = ga[miF][ni][reg], Gi = ga[miF + 2][ni][reg];
        gout[j * 32 + p]        = f2b(Gr * c - Gi * sn);
        gout[(32 + j) * 32 + p] = f2b(Gr * sn + Gi * c);
      }
    }

  if (lane == 0) cds[chain * 64 + g] = cdsv;
}

// ---------- K_b: inter-chunk scan (G -> H_pre, in place) ----------
__global__ __launch_bounds__(256) void k_chunkB(
    u16* __restrict__ GH, const float* __restrict__ cds,
    const float* __restrict__ omega, const float* __restrict__ A_log)
{
  const int tid = threadIdx.x, chain = blockIdx.x;
  const int h = chain & 31;
  const int j = tid & 31, pg = tid >> 5;        // pg 0..7 -> p = pg*4..+3
  const float om = omega[h * 32 + j];
  const float eA = expf(A_log[h]);
  float hr[4] = {0,0,0,0}, hi[4] = {0,0,0,0};
  const size_t base = (size_t)chain * 64 * 2048;

  for (int g = 0; g < 64; ++g) {
    u16* slot = GH + base + (size_t)g * 2048;
    // read this thread's G elements (bf16)
    uint2 grw = *(const uint2*)(slot + j * 32 + pg * 4);
    uint2 giw = *(const uint2*)(slot + (32 + j) * 32 + pg * 4);
    const float cdsv = cds[chain * 64 + g];
    __syncthreads();                       // all G reads done before H writes
    // write H_pre (carry-in for chunk g) in [32p][64f] layout
#pragma unroll
    for (int i = 0; i < 4; ++i) {
      const int p = pg * 4 + i;
      slot[p * 64 + j]      = f2b(hr[i]);
      slot[p * 64 + 32 + j] = f2b(hi[i]);
    }
    // update H <- P63*H + G
    const float dd = expf(-eA * cdsv);
    float sn, c; __sincosf(om * cdsv, &sn, &c);
    const float al = dd * c, be = dd * sn;
    const u32 gw[2] = {grw.x, grw.y};
    const u32 iw[2] = {giw.x, giw.y};
#pragma unroll
    for (int i = 0; i < 4; ++i) {
      const float Gr = (i & 1) ? hi2f(gw[i >> 1]) : lo2f(gw[i >> 1]);
      const float Gi = (i & 1) ? hi2f(iw[i >> 1]) : lo2f(iw[i >> 1]);
      const float r = al * hr[i] - be * hi[i] + Gr;
      const float m = be * hr[i] + al * hi[i] + Gi;
      hr[i] = r; hi[i] = m;
    }
    __syncthreads();                       // H writes done before next iter
  }
}

// ---------- K_c: intra-chunk attention + carry + fused gate ----------
__global__ __launch_bounds__(64) void k_chunkC(
    const float* __restrict__ dtb, const float* __restrict__ Bh,
    const float* __restrict__ Ch, u16* zxb,
    const u16* __restrict__ GH, const float* __restrict__ omega,
    const float* __restrict__ A_log, const float* __restrict__ Dp)
{
  __shared__ __attribute__((aligned(16))) u16 dtxT[2048];   // [32p][64s] swizzled
  __shared__ __attribute__((aligned(16))) u16 Mlds[4096];   // [64t][64s] swizzled
  __shared__ float sig_s[64];
  const int lane = threadIdx.x;
  const int gidx = blockIdx.x;
  const int chain = gidx >> 6, g = gidx & 63;
  const int b = chain >> 5, h = chain & 31;
  const size_t row0 = (size_t)b * TT + (size_t)g * 64;
  const int l15 = lane & 15, l4 = lane >> 4;
  const float eA = expf(A_log[h]);
  const float Dv = Dp[h];
  const f32x4 zero = {0.f,0.f,0.f,0.f};

  // per-lane t = lane: dt + prefix
  const size_t rowt = row0 + lane;
  const float dt = dtb[rowt * 32 + h];
  float sig = dt;
#pragma unroll
  for (int off = 1; off < 64; off <<= 1) {
    float o = __shfl_up(sig, off);
    if (lane >= off) sig += o;
  }
  sig_s[lane] = sig;

  // dtxT build
  const u16* xrow = zxb + rowt * NPAD + 1024 + h * 32;
  uint4 xa = *(const uint4*)xrow, xb = *(const uint4*)(xrow + 8),
        xc = *(const uint4*)(xrow + 16), xd = *(const uint4*)(xrow + 24);
  u32 xw[16] = {xa.x,xa.y,xa.z,xa.w, xb.x,xb.y,xb.z,xb.w,
                xc.x,xc.y,xc.z,xc.w, xd.x,xd.y,xd.z,xd.w};
#pragma unroll
  for (int p = 0; p < 32; ++p) {
    float xv = (p & 1) ? hi2f(xw[p >> 1]) : lo2f(xw[p >> 1]);
    *(u16*)((char*)dtxT + SWZ(p, 2 * lane)) = f2b(dt * xv);
  }
  __syncthreads();

  // phiC A-frags (kept for S and carry GEMMs)
  short8 fc[4][2];
#pragma unroll
  for (int mi = 0; mi < 4; ++mi) {
    const int t = mi * 16 + l15;
    const float st_ = sig_s[t];
    const float* crow = Ch + (row0 + t) * 64 + l4 * 16;
    float4 c0 = *(const float4*)crow, c1 = *(const float4*)(crow + 4),
           c2 = *(const float4*)(crow + 8), c3 = *(const float4*)(crow + 12);
    float CCv[16] = {c0.x,c0.y,c0.z,c0.w, c1.x,c1.y,c1.z,c1.w,
                     c2.x,c2.y,c2.z,c2.w, c3.x,c3.y,c3.z,c3.w};
    short cr8[8], ci8[8];
#pragma unroll
    for (int e = 0; e < 8; ++e) {
      const int j = l4 * 8 + e;
      const float om = omega[h * 32 + j];
      float sn, c; __sincosf(om * st_, &sn, &c);
      const float C0 = CCv[2 * e], C1 = CCv[2 * e + 1];
      cr8[e] = (short)f2b(C0 * c + C1 * sn);
      ci8[e] = (short)f2b(C0 * sn - C1 * c);
    }
    fc[mi][0] = mk8(cr8); fc[mi][1] = mk8(ci8);
  }

  // phiB B-frags
  short8 fb[4][2];
#pragma unroll
  for (int ni = 0; ni < 4; ++ni) {
    const int s = ni * 16 + l15;
    const float ss_ = sig_s[s];
    const float* brow = Bh + (row0 + s) * 64 + l4 * 16;
    float4 b0 = *(const float4*)brow, b1 = *(const float4*)(brow + 4),
           b2 = *(const float4*)(brow + 8), b3 = *(const float4*)(brow + 12);
    float BBv[16] = {b0.x,b0.y,b0.z,b0.w, b1.x,b1.y,b1.z,b1.w,
                     b2.x,b2.y,b2.z,b2.w, b3.x,b3.y,b3.z,b3.w};
    short br8[8], bi8[8];
#pragma unroll
    for (int e = 0; e < 8; ++e) {
      const int j = l4 * 8 + e;
      const float om = omega[h * 32 + j];
      float sn, c; __sincosf(om * ss_, &sn, &c);
      const float B0 = BBv[2 * e], B1 = BBv[2 * e + 1];
      br8[e] = (short)f2b(B0 * c + B1 * sn);
      bi8[e] = (short)f2b(B0 * sn - B1 * c);   // = -bi (sign folded)
    }
    fb[ni][0] = mk8(br8); fb[ni][1] = mk8(bi8);
  }

  // S = phiC @ phiB^T  [64x64]
  f32x4 sacc[4][4];
#pragma unroll
  for (int mi = 0; mi < 4; ++mi)
#pragma unroll
    for (int ni = 0; ni < 4; ++ni) sacc[mi][ni] = zero;
#pragma unroll
  for (int kk = 0; kk < 2; ++kk)
#pragma unroll
    for (int mi = 0; mi < 4; ++mi)
#pragma unroll
      for (int ni = 0; ni < 4; ++ni)
        sacc[mi][ni] = __builtin_amdgcn_mfma_f32_16x16x32_bf16(fc[mi][kk], fb[ni][kk], sacc[mi][ni], 0, 0, 0);

  // mask + decay -> M (bf16, swizzled LDS)
#pragma unroll
  for (int mi = 0; mi < 4; ++mi)
#pragma unroll
    for (int ni = 0; ni < 4; ++ni)
#pragma unroll
      for (int reg = 0; reg < 4; ++reg) {
        const int t = mi * 16 + l4 * 4 + reg;
        const int s = ni * 16 + l15;
        const float d = (s <= t) ? expf(-eA * (sig_s[t] - sig_s[s])) : 0.f;
        *(u16*)((char*)Mlds + SWZ(t, 2 * s)) = f2b(d * sacc[mi][ni][reg]);
      }
  __syncthreads();

  // Yint = M @ dtxT^T  [64t x 32p]
  f32x4 yi[4][2];
#pragma unroll
  for (int mi = 0; mi < 4; ++mi) { yi[mi][0] = zero; yi[mi][1] = zero; }
#pragma unroll
  for (int kk = 0; kk < 2; ++kk) {
    short8 db[2];
#pragma unroll
    for (int ni = 0; ni < 2; ++ni) {
      const int prow = ni * 16 + l15;
      db[ni] = *(const short8*)((const char*)dtxT + SWZ(prow, l4 * 16 + kk * 64));
    }
#pragma unroll
    for (int mi = 0; mi < 4; ++mi) {
      const int trow = mi * 16 + l15;
      short8 ma = *(const short8*)((const char*)Mlds + SWZ(trow, l4 * 16 + kk * 64));
#pragma unroll
      for (int ni = 0; ni < 2; ++ni)
        yi[mi][ni] = __builtin_amdgcn_mfma_f32_16x16x32_bf16(ma, db[ni], yi[mi][ni], 0, 0, 0);
    }
  }

  // Ycar = phiC @ phiH^T (H direct from global, [32p][64f] bf16)
  f32x4 yc[4][2];
#pragma unroll
  for (int mi = 0; mi < 4; ++mi) { yc[mi][0] = zero; yc[mi][1] = zero; }
  const u16* hbase = GH + (size_t)gidx * 2048;
#pragma unroll
  for (int kk = 0; kk < 2; ++kk) {
    short8 hb[2];
#pragma unroll
    for (int ni = 0; ni < 2; ++ni) {
      const int p = ni * 16 + l15;
      short8 v = *(const short8*)(hbase + p * 64 + l4 * 8 + kk * 32);
      hb[ni] = (kk == 1) ? neg8(v) : v;     // phiH = [hr | -hi]
    }
#pragma unroll
    for (int mi = 0; mi < 4; ++mi)
#pragma unroll
      for (int ni = 0; ni < 2; ++ni)
        yc[mi][ni] = __builtin_amdgcn_mfma_f32_16x16x32_bf16(fc[mi][kk], hb[ni], yc[mi][ni], 0, 0, 0);
  }

  // epilogue: y = Yint + exp(-eA sig_t)*Ycar ; v = (y + D*x)*z -> x-slice
#pragma unroll
  for (int mi = 0; mi < 4; ++mi)
#pragma unroll
    for (int reg = 0; reg < 4; ++reg) {
      const int t = mi * 16 + l4 * 4 + reg;
      const float scv = expf(-eA * sig_s[t]);
      const size_t rbase = (row0 + t) * NPAD;
#pragma unroll
      for (int ni = 0; ni < 2; ++ni) {
        const int p = ni * 16 + l15;
        const float y = yi[mi][ni][reg] + scv * yc[mi][ni][reg];
        const float xv = b2f(zxb[rbase + 1024 + h * 32 + p]);
        const float zv = b2f(zxb[rbase + h * 32 + p]);
        zxb[rbase + 1024 + h * 32 + p] = f2b((y + Dv * xv) * zv);
      }
    }
}

// ---------- launch ----------
extern "C" void kernel_launch(void* const* d_in, const int* in_sizes, int n_in,
                              void* d_out, int out_size, void* d_ws, size_t ws_size,
                              hipStream_t stream) {
  const float* input     = (const float*)d_in[0];
  const float* rms_w     = (const float*)d_in[1];
  const float* in_proj_W = (const float*)d_in[2];
  const float* dt_bias   = (const float*)d_in[3];
  const float* A_log     = (const float*)d_in[4];
  const float* omega     = (const float*)d_in[5];
  const float* Dp        = (const float*)d_in[6];
  const float* Bnw       = (const float*)d_in[7];
  const float* Cnw       = (const float*)d_in[8];
  const float* out_proj_W= (const float*)d_in[9];
  float* out = (float*)d_out;

  // ---- workspace layout (bytes), total 242,548,736 (~231.3 MB) ----
  const size_t NEED = 242548736;
  fprintf(stderr, "[kernel] ws_size=%zu need=%zu n_in=%d out_size=%d\n",
          ws_size, NEED, n_in, out_size);
  if (ws_size < NEED) return;

  char* ws = (char*)d_ws;
  u16*   zxb  = (u16*)(ws + 0);              // 150,994,944  bf16[BT][2304]
  u16*   nv   = (u16*)(ws + 150994944);      //  67,108,864  normed -> GH (16384 x 4KB)
  u16*   w1   = (u16*)(ws + 218103808);      //   2,359,296  bf16[2304][512]
  u16*   w2   = (u16*)(ws + 220463104);      //   1,048,576  bf16[512][1024]
  float* dtb  = (float*)(ws + 221511680);    //   4,194,304  f32[BT][32]
  float* Bh   = (float*)(ws + 225705984);    //   8,388,608  f32[BT][64]
  float* Ch   = (float*)(ws + 234094592);    //   8,388,608  f32[BT][64]
  float* cds  = (float*)(ws + 242483200);    //      65,536  f32[256][64]
  u16* normed = nv;
  u16* GH     = nv;

  k_wconv<<<6656, 256, 0, stream>>>(in_proj_W, out_proj_W, w1, w2);
  k_rms<<<BT, 64, 0, stream>>>(input, rms_w, normed);
  // GEMM1: [BT,512] @ [2304,512]^T -> zxb bf16 [BT,2304]
  k_gemm<<<(BT / 128) * 18, 256, 0, stream>>>(normed, w1, 512, 512, 16, 18,
                                              zxb, NPAD, nullptr, nullptr);
  k_derive<<<BT, 64, 0, stream>>>(zxb, dt_bias, Bnw, Cnw, dtb, Bh, Ch);
  // chunked SSD scan
  k_chunkA<<<16384, 64, 0, stream>>>(dtb, Bh, zxb, omega, A_log, GH, cds);
  k_chunkB<<<256, 256, 0, stream>>>(GH, cds, omega, A_log);
  k_chunkC<<<16384, 64, 0, stream>>>(dtb, Bh, Ch, zxb, GH, omega, A_log, Dp);
  // GEMM2: v (in zxb x-slice) @ [512,1024]^T + input -> out f32 [BT,512]
  k_gemm<<<(BT / 128) * 4, 256, 0, stream>>>(zxb + 1024, w2, NPAD, 1024, 32, 4,
                                             nullptr, 512, out, input);
}